// Round 3
// baseline (1497.093 us; speedup 1.0000x reference)
//
#include <hip/hip_runtime.h>

// GRU scan: T=2048 steps, B=2048 independent chains, latent=32, emb=64, vocab=97.
// Strategy:
//   prep_tables: E[m][v][j] = bias_m[j] + sum_k emb[v][k]*W_m[j][k]  (e-part folded
//                into a 97-row lookup table per gate; kills 2/3 of the FLOPs)
//   gru_main:    2 chains per wave (lane = (chain_half, j)); recurrent weights
//                (3 x 32 f32 per lane) in VGPRs; h / h*r broadcast via per-chain
//                LDS rows (stride 36 floats -> conflict-free writes, broadcast reads);
//                E rows prefetched 1 step ahead, x prefetched 2 ahead, branch-free.

#define T_STEPS 2048
#define BATCH   2048
#define VOCAB   97
#define EMBD    64
#define LATENT  32
#define ROWPAD  36   // 144B row stride: 16B-aligned, banks (4c+j)%32 -> conflict-free

__device__ __forceinline__ float fast_rcp(float x) { return __builtin_amdgcn_rcpf(x); }

__global__ void prep_tables(const float* __restrict__ emb,
                            const float* __restrict__ Wz, const float* __restrict__ bz,
                            const float* __restrict__ Wr, const float* __restrict__ br,
                            const float* __restrict__ Wh, const float* __restrict__ bh,
                            float* __restrict__ E) {
    int id = blockIdx.x * blockDim.x + threadIdx.x;
    if (id >= VOCAB * 96) return;
    int v   = id / 96;
    int rem = id % 96;
    int m   = rem >> 5;   // 0:z 1:r 2:h
    int j   = rem & 31;
    const float* W = (m == 0) ? Wz : ((m == 1) ? Wr : Wh);
    const float* b = (m == 0) ? bz : ((m == 1) ? br : bh);
    float s = b[j];
    const float* er = emb + v * EMBD;
    const float* wr = W + j * 96;         // e-part = first 64 columns
    #pragma unroll 16
    for (int k = 0; k < EMBD; ++k) s += er[k] * wr[k];
    E[m * (VOCAB * LATENT) + v * LATENT + j] = s;
}

// inline fn, NOT a macro: a macro parameter named `w` collides with float4's
// `.w` member under token substitution (round-2 compile failure).
__device__ __forceinline__ void dot4(float& a0, float& a1, const float4& q, const float4& wv) {
    a0 += q.x * wv.x; a1 += q.y * wv.y;
    a0 += q.z * wv.z; a1 += q.w * wv.w;
}

__global__ __launch_bounds__(256, 1) void gru_main(
    const int*   __restrict__ x,
    const float* __restrict__ h0,
    const float* __restrict__ Wz,
    const float* __restrict__ Wr,
    const float* __restrict__ Wh,
    const float* __restrict__ E,
    float*       __restrict__ out)
{
    __shared__ __align__(16) float sh_h [8][ROWPAD];
    __shared__ __align__(16) float sh_hr[8][ROWPAD];

    const int tid  = threadIdx.x;
    const int lane = tid & 63;
    const int wave = tid >> 6;
    const int c    = lane >> 5;          // chain within wave (0/1)
    const int j    = lane & 31;          // output index
    const int cb   = wave * 2 + c;       // chain slot in block (0..7)
    const int chain = blockIdx.x * 8 + cb;

    // --- preload recurrent weight rows into VGPRs (h-part = columns 64..95) ---
    float4 wz4[8], wr4[8], wh4[8];
    {
        const float4* pz = reinterpret_cast<const float4*>(Wz + j * 96 + 64);
        const float4* pr = reinterpret_cast<const float4*>(Wr + j * 96 + 64);
        const float4* ph = reinterpret_cast<const float4*>(Wh + j * 96 + 64);
        #pragma unroll
        for (int i = 0; i < 8; ++i) { wz4[i] = pz[i]; wr4[i] = pr[i]; wh4[i] = ph[i]; }
    }

    const float* Ez = E;
    const float* Er = E + VOCAB * LATENT;
    const float* Eh = E + 2 * VOCAB * LATENT;

    float hval = h0[chain * LATENT + j];
    sh_h[cb][j] = hval;

    // software pipeline: x two steps ahead, E rows one step ahead
    int xc = x[chain];                       // x[0]
    int xn = x[BATCH + chain];               // x[1]
    float ez = Ez[xc * LATENT + j];
    float er = Er[xc * LATENT + j];
    float eh = Eh[xc * LATENT + j];

    float* outp = out + chain * LATENT + j;

    const float4* hrow  = reinterpret_cast<const float4*>(&sh_h [cb][0]);
    const float4* hrrow = reinterpret_cast<const float4*>(&sh_hr[cb][0]);

    #pragma unroll 1
    for (int t = 0; t < T_STEPS; ++t) {
        // broadcast-read current h (all 32 lanes of a chain hit the same addr)
        float4 h0q = hrow[0], h1q = hrow[1], h2q = hrow[2], h3q = hrow[3];
        float4 h4q = hrow[4], h5q = hrow[5], h6q = hrow[6], h7q = hrow[7];

        // prefetch x[t+2] (clamped, branch-free)
        int t2 = t + 2; t2 = (t2 < T_STEPS) ? t2 : (T_STEPS - 1);
        int xn2 = x[t2 * BATCH + chain];

        float az0 = 0.f, az1 = 0.f, ar0 = 0.f, ar1 = 0.f;
        dot4(az0, az1, h0q, wz4[0]); dot4(ar0, ar1, h0q, wr4[0]);
        dot4(az0, az1, h1q, wz4[1]); dot4(ar0, ar1, h1q, wr4[1]);
        dot4(az0, az1, h2q, wz4[2]); dot4(ar0, ar1, h2q, wr4[2]);
        dot4(az0, az1, h3q, wz4[3]); dot4(ar0, ar1, h3q, wr4[3]);
        dot4(az0, az1, h4q, wz4[4]); dot4(ar0, ar1, h4q, wr4[4]);
        dot4(az0, az1, h5q, wz4[5]); dot4(ar0, ar1, h5q, wr4[5]);
        dot4(az0, az1, h6q, wz4[6]); dot4(ar0, ar1, h6q, wr4[6]);
        dot4(az0, az1, h7q, wz4[7]); dot4(ar0, ar1, h7q, wr4[7]);

        float az = az0 + az1 + ez;
        float ar = ar0 + ar1 + er;
        float zg = fast_rcp(1.f + __expf(-az));
        float rg = fast_rcp(1.f + __expf(-ar));

        float hr = hval * rg;
        sh_hr[cb][j] = hr;

        // prefetch E rows for step t+1 (xn arrived during step t-1)
        float ezn = Ez[xn * LATENT + j];
        float ern = Er[xn * LATENT + j];
        float ehn = Eh[xn * LATENT + j];

        float4 g0q = hrrow[0], g1q = hrrow[1], g2q = hrrow[2], g3q = hrrow[3];
        float4 g4q = hrrow[4], g5q = hrrow[5], g6q = hrrow[6], g7q = hrrow[7];

        float ah0 = 0.f, ah1 = 0.f;
        dot4(ah0, ah1, g0q, wh4[0]);
        dot4(ah0, ah1, g1q, wh4[1]);
        dot4(ah0, ah1, g2q, wh4[2]);
        dot4(ah0, ah1, g3q, wh4[3]);
        dot4(ah0, ah1, g4q, wh4[4]);
        dot4(ah0, ah1, g5q, wh4[5]);
        dot4(ah0, ah1, g6q, wh4[6]);
        dot4(ah0, ah1, g7q, wh4[7]);

        float ah = ah0 + ah1 + eh;
        float ex = __expf(-2.f * ah);                // tanh = (1-e^-2a)/(1+e^-2a)
        float ht = (1.f - ex) * fast_rcp(1.f + ex);

        hval = hval + zg * (ht - hval);
        sh_h[cb][j] = hval;
        outp[t * (BATCH * LATENT)] = hval;

        ez = ezn; er = ern; eh = ehn;
        xc = xn; xn = xn2;
    }
}

extern "C" void kernel_launch(void* const* d_in, const int* in_sizes, int n_in,
                              void* d_out, int out_size, void* d_ws, size_t ws_size,
                              hipStream_t stream) {
    const int*   x   = (const int*)  d_in[0];
    const float* h   = (const float*)d_in[1];
    const float* emb = (const float*)d_in[2];
    const float* Wz  = (const float*)d_in[3];
    const float* bz  = (const float*)d_in[4];
    const float* Wr  = (const float*)d_in[5];
    const float* br  = (const float*)d_in[6];
    const float* Wh  = (const float*)d_in[7];
    const float* bh  = (const float*)d_in[8];
    float* out = (float*)d_out;
    float* E   = (float*)d_ws;   // 3 * 97 * 32 floats = 37 KB

    prep_tables<<<(VOCAB * 96 + 255) / 256, 256, 0, stream>>>(emb, Wz, bz, Wr, br, Wh, bh, E);
    gru_main<<<BATCH / 8, 256, 0, stream>>>(x, h, Wz, Wr, Wh, E, out);
}